// Round 1
// baseline (534.805 us; speedup 1.0000x reference)
//
#include <hip/hip_runtime.h>
#include <hip/hip_bf16.h>
#include <cstdint>
#include <cstddef>

#define K2V 36864   // (3*64)^2
#define MN  1024    // nodes
#define HF  768     // HORIZON * H_FSIZE

typedef __attribute__((ext_vector_type(8))) short short8;   // 8 bf16 (4 VGPR)
typedef __attribute__((ext_vector_type(4))) float f32x4;    // MFMA acc

__device__ __forceinline__ unsigned pk_bf2(float a, float b) {
    __hip_bfloat16 ha = __float2bfloat16(a);
    __hip_bfloat16 hb = __float2bfloat16(b);
    unsigned short ua = *reinterpret_cast<unsigned short*>(&ha);
    unsigned short ub = *reinterpret_cast<unsigned short*>(&hb);
    return (unsigned)ua | ((unsigned)ub << 16);
}

// Stage 1: h_partial[ksplit][1024][768] = weights @ W_hyp^T  (split-K partials)
// A = weights (1024 x 36864) row-major, B = W_hyp (768 x 36864) row-major (NT form).
// 128x128 tile, BK=64, 4 waves (2x2), 16x16x32 bf16 MFMA, f32->bf16 cvt at staging,
// XOR-swizzled bf16 LDS, double-buffered, 1 barrier per K-step.
__global__ __launch_bounds__(256, 2)
void gemm_h_split(const float* __restrict__ A, const float* __restrict__ B,
                  float* __restrict__ part, int KC)
{
    __shared__ unsigned short sA[2][128 * 64];
    __shared__ unsigned short sB[2][128 * 64];

    const int tid  = threadIdx.x;
    const int lane = tid & 63;
    const int wave = tid >> 6;
    const int wm   = wave >> 1;   // 0..1
    const int wn   = wave & 1;    // 0..1

    const int mtile = blockIdx.x / 6;
    const int ntile = blockIdx.x % 6;
    const int k0    = blockIdx.y * KC;

    const float* Ap = A + (size_t)(mtile * 128) * K2V + k0;
    const float* Bp = B + (size_t)(ntile * 128) * K2V + k0;

    const int c4 = tid & 15;   // float4 column within BK=64 (16 cols of float4)
    const int rt = tid >> 4;   // 0..15 (row group; rows rt+16*i)

    f32x4 acc[4][4];
    #pragma unroll
    for (int i = 0; i < 4; ++i)
        #pragma unroll
        for (int j = 0; j < 4; ++j)
            acc[i][j] = (f32x4){0.f, 0.f, 0.f, 0.f};

    float4 ra[8], rb[8];

    auto load_step = [&](int s) {
        const float* a = Ap + s * 64 + c4 * 4;
        const float* b = Bp + s * 64 + c4 * 4;
        #pragma unroll
        for (int i = 0; i < 8; ++i) {
            const int r = rt + 16 * i;
            ra[i] = *reinterpret_cast<const float4*>(a + (size_t)r * K2V);
            rb[i] = *reinterpret_cast<const float4*>(b + (size_t)r * K2V);
        }
    };
    auto write_step = [&](int buf) {
        #pragma unroll
        for (int i = 0; i < 8; ++i) {
            const int r = rt + 16 * i;
            int off = r * 128 + c4 * 8;      // byte offset in a [128][64] bf16 tile
            off ^= (r & 7) << 4;             // bank swizzle (G4/T2), 8B-write safe
            uint2 va = { pk_bf2(ra[i].x, ra[i].y), pk_bf2(ra[i].z, ra[i].w) };
            uint2 vb = { pk_bf2(rb[i].x, rb[i].y), pk_bf2(rb[i].z, rb[i].w) };
            *reinterpret_cast<uint2*>(reinterpret_cast<char*>(sA[buf]) + off) = va;
            *reinterpret_cast<uint2*>(reinterpret_cast<char*>(sB[buf]) + off) = vb;
        }
    };

    const int nsteps = KC >> 6;

    load_step(0);
    write_step(0);
    __syncthreads();

    for (int s = 0; s < nsteps; ++s) {
        if (s + 1 < nsteps) load_step(s + 1);   // issue next-tile loads early (T14-lite)
        const int buf = s & 1;
        #pragma unroll
        for (int ks = 0; ks < 2; ++ks) {
            short8 av[4], bv[4];
            const int cb = (ks * 32 + (lane >> 4) * 8) * 2;   // byte col in tile row
            #pragma unroll
            for (int i = 0; i < 4; ++i) {
                const int rA = wm * 64 + i * 16 + (lane & 15);
                const int rB = wn * 64 + i * 16 + (lane & 15);
                int oa = rA * 128 + cb; oa ^= (rA & 7) << 4;
                int ob = rB * 128 + cb; ob ^= (rB & 7) << 4;
                av[i] = *reinterpret_cast<const short8*>(reinterpret_cast<const char*>(sA[buf]) + oa);
                bv[i] = *reinterpret_cast<const short8*>(reinterpret_cast<const char*>(sB[buf]) + ob);
            }
            #pragma unroll
            for (int i = 0; i < 4; ++i)
                #pragma unroll
                for (int j = 0; j < 4; ++j)
                    acc[i][j] = __builtin_amdgcn_mfma_f32_16x16x32_bf16(av[i], bv[j], acc[i][j], 0, 0, 0);
        }
        // writes go to buf^1 (disjoint from reads of buf) -> single barrier per step
        if (s + 1 < nsteps) write_step((s + 1) & 1);
        __syncthreads();
    }

    // C/D layout of 16x16x32: col = lane&15, row = (lane>>4)*4 + q  [m89/m91]
    float* P = part + ((size_t)blockIdx.y * MN + mtile * 128 + wm * 64) * HF
                    + ntile * 128 + wn * 64;
    #pragma unroll
    for (int i = 0; i < 4; ++i) {
        #pragma unroll
        for (int j = 0; j < 4; ++j) {
            const int col = j * 16 + (lane & 15);
            #pragma unroll
            for (int q = 0; q < 4; ++q) {
                const int row = i * 16 + (lane >> 4) * 4 + q;
                P[(size_t)row * HF + col] = acc[i][j][q];
            }
        }
    }
}

// Stage 2: one block per node n.
// Reduce split-K partials + bias into h_n (LDS), stage x_n = output[:,11,n,:] (LDS),
// then out[b,t,n] = sum_f x[b,f] * h[t*64+f].
__global__ __launch_bounds__(256)
void hyper_out(const float* __restrict__ xall, const float* __restrict__ part,
               const float* __restrict__ bias, float* __restrict__ out, int ksplit)
{
    const int n   = blockIdx.x;
    const int tid = threadIdx.x;
    __shared__ float hs[HF];
    __shared__ float xs[64 * 65];   // pad 65: lane b -> bank (b+f)%32, 2-way max (free)

    #pragma unroll
    for (int jj = 0; jj < 3; ++jj) {
        const int j = tid + jj * 256;
        float s = bias[j];
        for (int k = 0; k < ksplit; ++k)
            s += part[((size_t)k * MN + n) * HF + j];
        hs[j] = s;
    }
    {
        const int c4 = tid & 15;
        const int bt = tid >> 4;
        #pragma unroll
        for (int i = 0; i < 4; ++i) {
            const int b = bt + 16 * i;
            const float4 v = *reinterpret_cast<const float4*>(
                xall + ((size_t)(b * 12 + 11) * MN + n) * 64 + c4 * 4);
            xs[b * 65 + c4 * 4 + 0] = v.x;
            xs[b * 65 + c4 * 4 + 1] = v.y;
            xs[b * 65 + c4 * 4 + 2] = v.z;
            xs[b * 65 + c4 * 4 + 3] = v.w;
        }
    }
    __syncthreads();

    // lane b = tid&63 (one x-row per thread), t0 = tid>>6; thread covers t0, t0+4, t0+8.
    // hs reads are wave-uniform (broadcast, conflict-free).
    const int b  = tid & 63;
    const int t0 = tid >> 6;
    float a0 = 0.f, a1 = 0.f, a2 = 0.f;
    #pragma unroll
    for (int f = 0; f < 64; ++f) {
        const float x = xs[b * 65 + f];
        a0 += x * hs[t0 * 64 + f];
        a1 += x * hs[(t0 + 4) * 64 + f];
        a2 += x * hs[(t0 + 8) * 64 + f];
    }
    out[((size_t)(b * 12 + t0)) * MN + n]     = a0;
    out[((size_t)(b * 12 + t0 + 4)) * MN + n] = a1;
    out[((size_t)(b * 12 + t0 + 8)) * MN + n] = a2;
}

extern "C" void kernel_launch(void* const* d_in, const int* in_sizes, int n_in,
                              void* d_out, int out_size, void* d_ws, size_t ws_size,
                              hipStream_t stream)
{
    const float* xall = (const float*)d_in[0];  // output (64,12,1024,64)
    const float* wts  = (const float*)d_in[1];  // weights (1024,36864)
    const float* Whyp = (const float*)d_in[2];  // W_hyp (768,36864)
    const float* bhyp = (const float*)d_in[3];  // b_hyp (768)
    float* out  = (float*)d_out;
    float* part = (float*)d_ws;

    // split-K partials: ksplit * 1024*768 f32 in ws; pick largest that fits.
    // all options divide 576 so KC is a multiple of 64.
    const size_t slice = (size_t)MN * HF * sizeof(float);
    int ks = 1;
    const int opts[8] = {16, 12, 8, 6, 4, 3, 2, 1};
    for (int i = 0; i < 8; ++i) {
        if ((size_t)opts[i] * slice <= ws_size) { ks = opts[i]; break; }
    }
    const int KC = K2V / ks;

    dim3 g1(48, ks);
    gemm_h_split<<<g1, dim3(256), 0, stream>>>(wts, Whyp, part, KC);
    hyper_out<<<dim3(1024), dim3(256), 0, stream>>>(xall, part, bhyp, out, ks);
}

// Round 2
// 509.089 us; speedup vs baseline: 1.0505x; 1.0505x over previous
//
#include <hip/hip_runtime.h>
#include <hip/hip_bf16.h>
#include <cstdint>
#include <cstddef>

#define K2V 36864   // (3*64)^2
#define MN  1024    // nodes
#define HF  768     // HORIZON * H_FSIZE

typedef __attribute__((ext_vector_type(8))) short short8;   // 8 bf16 (4 VGPR)
typedef __attribute__((ext_vector_type(4))) float f32x4;    // MFMA acc

__device__ __forceinline__ unsigned pk_bf2(float a, float b) {
    __hip_bfloat16 ha = __float2bfloat16(a);
    __hip_bfloat16 hb = __float2bfloat16(b);
    unsigned short ua = *reinterpret_cast<unsigned short*>(&ha);
    unsigned short ub = *reinterpret_cast<unsigned short*>(&hb);
    return (unsigned)ua | ((unsigned)ub << 16);
}

// Stage 1: part[ksplit][1024][768] = weights @ W_hyp^T  (split-K partials)
// 128x128 tile, BK=64, 8 waves (2x4), 512 threads, 16x16x32 bf16 MFMA.
// f32->bf16 cvt at staging, XOR-swizzled LDS, double-buffered, 1 barrier/step.
// XCD-chunked block mapping: mtile = blockIdx.x & 7 (one A row-panel per XCD).
__global__ __launch_bounds__(512, 4)
void gemm_h_split(const float* __restrict__ A, const float* __restrict__ B,
                  float* __restrict__ part, int KC)
{
    __shared__ unsigned short sA[2][128 * 64];   // 2 x 16KB
    __shared__ unsigned short sB[2][128 * 64];   // 2 x 16KB

    const int tid  = threadIdx.x;
    const int lane = tid & 63;
    const int wave = tid >> 6;    // 0..7
    const int wm   = wave >> 2;   // 0..1 (row of 64)
    const int wn   = wave & 3;    // 0..3 (col of 32)

    // XCD-aware chunked mapping (HW: XCD = linear blockIdx % 8).
    int mtile, ntile, kidx;
    if ((gridDim.x & 7) == 0) {
        const int xcd = blockIdx.x & 7;
        const int pos = blockIdx.x >> 3;      // 0 .. 6*ks-1
        mtile = xcd;                          // 8 mtiles == 8 XCDs
        kidx  = pos / 6;
        ntile = pos - kidx * 6;
    } else {
        kidx = blockIdx.x / 48;
        const int rem = blockIdx.x - kidx * 48;
        mtile = rem / 6;
        ntile = rem - mtile * 6;
    }
    const int k0 = kidx * KC;

    const float* Ap = A + (size_t)(mtile * 128) * K2V + k0;
    const float* Bp = B + (size_t)(ntile * 128) * K2V + k0;

    const int c4 = tid & 15;   // float4 col within BK=64
    const int r0 = tid >> 4;   // 0..31; rows r0 + 32*i

    f32x4 acc[4][2];
    #pragma unroll
    for (int i = 0; i < 4; ++i)
        #pragma unroll
        for (int j = 0; j < 2; ++j)
            acc[i][j] = (f32x4){0.f, 0.f, 0.f, 0.f};

    float4 ra[4], rb[4];

    auto load_step = [&](int s) {
        const float* a = Ap + s * 64 + c4 * 4;
        const float* b = Bp + s * 64 + c4 * 4;
        #pragma unroll
        for (int i = 0; i < 4; ++i) {
            const int r = r0 + 32 * i;
            ra[i] = *reinterpret_cast<const float4*>(a + (size_t)r * K2V);
            rb[i] = *reinterpret_cast<const float4*>(b + (size_t)r * K2V);
        }
    };
    auto write_step = [&](int buf) {
        #pragma unroll
        for (int i = 0; i < 4; ++i) {
            const int r = r0 + 32 * i;
            int off = r * 128 + c4 * 8;      // byte offset in [128][64] bf16 tile
            off ^= (r & 7) << 4;             // st_16x32-style swizzle (T2)
            uint2 va = { pk_bf2(ra[i].x, ra[i].y), pk_bf2(ra[i].z, ra[i].w) };
            uint2 vb = { pk_bf2(rb[i].x, rb[i].y), pk_bf2(rb[i].z, rb[i].w) };
            *reinterpret_cast<uint2*>(reinterpret_cast<char*>(sA[buf]) + off) = va;
            *reinterpret_cast<uint2*>(reinterpret_cast<char*>(sB[buf]) + off) = vb;
        }
    };

    const int nsteps = KC >> 6;

    load_step(0);
    write_step(0);
    __syncthreads();

    for (int s = 0; s < nsteps; ++s) {
        if (s + 1 < nsteps) load_step(s + 1);   // issue next loads early (T14-lite)
        const int buf = s & 1;
        #pragma unroll
        for (int ks = 0; ks < 2; ++ks) {
            short8 av[4], bv[2];
            const int cb = (ks * 32 + (lane >> 4) * 8) * 2;   // byte col in row
            #pragma unroll
            for (int i = 0; i < 4; ++i) {
                const int rA = wm * 64 + i * 16 + (lane & 15);
                int oa = rA * 128 + cb; oa ^= (rA & 7) << 4;
                av[i] = *reinterpret_cast<const short8*>(reinterpret_cast<const char*>(sA[buf]) + oa);
            }
            #pragma unroll
            for (int j = 0; j < 2; ++j) {
                const int rB = wn * 32 + j * 16 + (lane & 15);
                int ob = rB * 128 + cb; ob ^= (rB & 7) << 4;
                bv[j] = *reinterpret_cast<const short8*>(reinterpret_cast<const char*>(sB[buf]) + ob);
            }
            #pragma unroll
            for (int i = 0; i < 4; ++i)
                #pragma unroll
                for (int j = 0; j < 2; ++j)
                    acc[i][j] = __builtin_amdgcn_mfma_f32_16x16x32_bf16(av[i], bv[j], acc[i][j], 0, 0, 0);
        }
        if (s + 1 < nsteps) write_step((s + 1) & 1);   // disjoint from buf reads
        __syncthreads();
    }

    // C/D: col = lane&15, row = (lane>>4)*4 + q  [m89/m91]
    float* P = part + ((size_t)kidx * MN + mtile * 128 + wm * 64) * HF
                    + ntile * 128 + wn * 32;
    #pragma unroll
    for (int i = 0; i < 4; ++i) {
        #pragma unroll
        for (int j = 0; j < 2; ++j) {
            const int col = j * 16 + (lane & 15);
            #pragma unroll
            for (int q = 0; q < 4; ++q) {
                const int row = i * 16 + (lane >> 4) * 4 + q;
                P[(size_t)row * HF + col] = acc[i][j][q];
            }
        }
    }
}

// Stage 2a: reduce split-K partials + bias, in place into part[0] slice.
// One float4 output per thread; 4 independent accumulator chains for MLP.
__global__ __launch_bounds__(256)
void h_reduce(float* __restrict__ part, const float* __restrict__ bias, int ksplit)
{
    const int fidx = blockIdx.x * 256 + threadIdx.x;   // float4 index, 196608 total
    const int n  = fidx / 192;
    const int j4 = fidx - n * 192;
    const size_t base = (size_t)n * HF + j4 * 4;
    const size_t kstride = (size_t)MN * HF;

    float4 s0 = *reinterpret_cast<const float4*>(bias + j4 * 4);
    float4 s1 = {0.f, 0.f, 0.f, 0.f}, s2 = {0.f, 0.f, 0.f, 0.f}, s3 = {0.f, 0.f, 0.f, 0.f};
    int k = 0;
    for (; k + 4 <= ksplit; k += 4) {
        float4 p0 = *reinterpret_cast<const float4*>(part + (size_t)(k + 0) * kstride + base);
        float4 p1 = *reinterpret_cast<const float4*>(part + (size_t)(k + 1) * kstride + base);
        float4 p2 = *reinterpret_cast<const float4*>(part + (size_t)(k + 2) * kstride + base);
        float4 p3 = *reinterpret_cast<const float4*>(part + (size_t)(k + 3) * kstride + base);
        s0.x += p0.x; s0.y += p0.y; s0.z += p0.z; s0.w += p0.w;
        s1.x += p1.x; s1.y += p1.y; s1.z += p1.z; s1.w += p1.w;
        s2.x += p2.x; s2.y += p2.y; s2.z += p2.z; s2.w += p2.w;
        s3.x += p3.x; s3.y += p3.y; s3.z += p3.z; s3.w += p3.w;
    }
    for (; k < ksplit; ++k) {
        float4 p0 = *reinterpret_cast<const float4*>(part + (size_t)k * kstride + base);
        s0.x += p0.x; s0.y += p0.y; s0.z += p0.z; s0.w += p0.w;
    }
    float4 r;
    r.x = (s0.x + s1.x) + (s2.x + s3.x);
    r.y = (s0.y + s1.y) + (s2.y + s3.y);
    r.z = (s0.z + s1.z) + (s2.z + s3.z);
    r.w = (s0.w + s1.w) + (s2.w + s3.w);
    *reinterpret_cast<float4*>(part + base) = r;   // thread-exclusive in-place write
}

// Stage 2b: one block per node n. hred = reduced h (part slice 0).
// out[b,t,n] = sum_f x[b,f] * h[t*64+f]
__global__ __launch_bounds__(256)
void hyper_out(const float* __restrict__ xall, const float* __restrict__ hred,
               float* __restrict__ out)
{
    const int n   = blockIdx.x;
    const int tid = threadIdx.x;
    __shared__ float hs[HF];
    __shared__ float xs[64 * 65];   // pad 65: 2-way max (free)

    #pragma unroll
    for (int jj = 0; jj < 3; ++jj) {
        const int j = tid + jj * 256;
        hs[j] = hred[(size_t)n * HF + j];
    }
    {
        const int c4 = tid & 15;
        const int bt = tid >> 4;
        #pragma unroll
        for (int i = 0; i < 4; ++i) {
            const int b = bt + 16 * i;
            const float4 v = *reinterpret_cast<const float4*>(
                xall + ((size_t)(b * 12 + 11) * MN + n) * 64 + c4 * 4);
            xs[b * 65 + c4 * 4 + 0] = v.x;
            xs[b * 65 + c4 * 4 + 1] = v.y;
            xs[b * 65 + c4 * 4 + 2] = v.z;
            xs[b * 65 + c4 * 4 + 3] = v.w;
        }
    }
    __syncthreads();

    const int b  = tid & 63;
    const int t0 = tid >> 6;
    float a0 = 0.f, a1 = 0.f, a2 = 0.f;
    #pragma unroll
    for (int f = 0; f < 64; ++f) {
        const float x = xs[b * 65 + f];
        a0 += x * hs[t0 * 64 + f];
        a1 += x * hs[(t0 + 4) * 64 + f];
        a2 += x * hs[(t0 + 8) * 64 + f];
    }
    out[((size_t)(b * 12 + t0)) * MN + n]     = a0;
    out[((size_t)(b * 12 + t0 + 4)) * MN + n] = a1;
    out[((size_t)(b * 12 + t0 + 8)) * MN + n] = a2;
}

extern "C" void kernel_launch(void* const* d_in, const int* in_sizes, int n_in,
                              void* d_out, int out_size, void* d_ws, size_t ws_size,
                              hipStream_t stream)
{
    const float* xall = (const float*)d_in[0];  // output (64,12,1024,64)
    const float* wts  = (const float*)d_in[1];  // weights (1024,36864)
    const float* Whyp = (const float*)d_in[2];  // W_hyp (768,36864)
    const float* bhyp = (const float*)d_in[3];  // b_hyp (768)
    float* out  = (float*)d_out;
    float* part = (float*)d_ws;

    // split-K partials: ksplit * 1024*768 f32 in ws; pick largest that fits.
    const size_t slice = (size_t)MN * HF * sizeof(float);
    int ks = 1;
    const int opts[8] = {16, 12, 8, 6, 4, 3, 2, 1};
    for (int i = 0; i < 8; ++i) {
        if ((size_t)opts[i] * slice <= ws_size) { ks = opts[i]; break; }
    }
    const int KC = K2V / ks;

    gemm_h_split<<<dim3(48 * ks), dim3(512), 0, stream>>>(wts, Whyp, part, KC);
    h_reduce<<<dim3(768), dim3(256), 0, stream>>>(part, bhyp, ks);
    hyper_out<<<dim3(1024), dim3(256), 0, stream>>>(xall, part, out);
}